// Round 1
// baseline (1581.608 us; speedup 1.0000x reference)
//
#include <hip/hip_runtime.h>
#include <math.h>

#define BB 4
#define CC 256
#define CKK 32
#define NN 4096
#define NT 16   // output columns per block
#define TI 32   // key tile

// ---------------- projection kernel: f = Wq x + bq, g = Wk x + bk, h = Wv x + bv ----
__global__ __launch_bounds__(256) void proj_kernel(
    const float* __restrict__ x,
    const float* __restrict__ Wq, const float* __restrict__ bq,
    const float* __restrict__ Wk, const float* __restrict__ bk,
    const float* __restrict__ Wv, const float* __restrict__ bv,
    float* __restrict__ f, float* __restrict__ g, float* __restrict__ h)
{
    __shared__ float xs[CC][17];
    const int t = threadIdx.x;
    const int b = blockIdx.x / (NN / NT);
    const int n0 = (blockIdx.x % (NN / NT)) * NT;

    // load x tile [256][16] (each thread: one channel row, 4 x float4)
    {
        const float4* xp = (const float4*)(x + ((size_t)b * CC + t) * NN + n0);
        #pragma unroll
        for (int q = 0; q < NT / 4; ++q) {
            float4 v = xp[q];
            xs[t][q * 4 + 0] = v.x; xs[t][q * 4 + 1] = v.y;
            xs[t][q * 4 + 2] = v.z; xs[t][q * 4 + 3] = v.w;
        }
    }
    __syncthreads();

    const int n = t & (NT - 1);
    const int rsub = t >> 4;   // 0..15
    for (int riter = 0; riter < 20; ++riter) {
        int row = riter * 16 + rsub;           // 0..319
        const float* Wrow; float bias; float* dst;
        if (row < 32)      { Wrow = Wq + (size_t)row * CC;        bias = bq[row];
                             dst = f + ((size_t)b * CKK + row) * NN; }
        else if (row < 64) { Wrow = Wk + (size_t)(row - 32) * CC; bias = bk[row - 32];
                             dst = g + ((size_t)b * CKK + (row - 32)) * NN; }
        else               { Wrow = Wv + (size_t)(row - 64) * CC; bias = bv[row - 64];
                             dst = h + ((size_t)b * CC + (row - 64)) * NN; }
        float acc = bias;
        #pragma unroll 8
        for (int c = 0; c < CC; c += 4) {
            float4 w = *(const float4*)(Wrow + c);
            acc += w.x * xs[c][n] + w.y * xs[c + 1][n]
                 + w.z * xs[c + 2][n] + w.w * xs[c + 3][n];
        }
        dst[n0 + n] = acc;
    }
}

// ---------------- fused attention: per block = (b, 16 output columns j) -------------
// For output column j: scores s_i = f[:,i].g[:,j]; softmax over i; o[:,j] = sum_i p_i h[:,i]
__global__ __launch_bounds__(256) void attn_kernel(
    const float* __restrict__ f, const float* __restrict__ g,
    const float* __restrict__ h, const float* __restrict__ gamma,
    float* __restrict__ out)
{
    __shared__ float gs[CKK][NT];        // query tile   (g columns j0..j0+15)
    __shared__ float fs[CKK][TI + 1];    // key tile
    __shared__ float hs[CC][TI + 4];     // value tile, stride 36 (16B-aligned rows)
    __shared__ float pt[NT][TI + 4];     // scores/probs, j-major, stride 36
    __shared__ float mj[NT], lj[NT], aj[NT];

    const int t = threadIdx.x;
    const int b = blockIdx.x / (NN / NT);
    const int j0 = (blockIdx.x % (NN / NT)) * NT;
    const int j = t & (NT - 1);
    const int csub = t >> 4;             // 0..15; thread owns c = csub + 16*cc

    // load g tile (32x16)
    #pragma unroll
    for (int q = 0; q < 2; ++q) {
        int idx = t + q * 256;
        int k = idx >> 4, jj = idx & (NT - 1);
        gs[k][jj] = g[((size_t)b * CKK + k) * NN + j0 + jj];
    }
    if (t < NT) { mj[t] = -1e30f; lj[t] = 0.f; }
    float acc[16];
    #pragma unroll
    for (int cc = 0; cc < 16; ++cc) acc[cc] = 0.f;
    __syncthreads();

    for (int i0 = 0; i0 < NN; i0 += TI) {
        // stage f tile (32x32), coalesced
        #pragma unroll
        for (int q = 0; q < 4; ++q) {
            int idx = q * 256 + t;
            fs[idx >> 5][idx & 31] = f[((size_t)b * CKK + (idx >> 5)) * NN + i0 + (idx & 31)];
        }
        // stage h tile (256x32), coalesced
        #pragma unroll
        for (int q = 0; q < 32; ++q) {
            int idx = q * 256 + t;
            hs[idx >> 5][idx & 31] = h[((size_t)b * CC + (idx >> 5)) * NN + i0 + (idx & 31)];
        }
        __syncthreads();

        // scores: 2 per thread, raw s -> pt[j][i]
        #pragma unroll
        for (int q = 0; q < 2; ++q) {
            int idx = t + q * 256;
            int i = idx >> 4, jj = idx & (NT - 1);
            float s = 0.f;
            #pragma unroll
            for (int k = 0; k < CKK; ++k) s += fs[k][i] * gs[k][jj];
            pt[jj][i] = s;
        }
        __syncthreads();

        // per-column running max + rescale factor
        if (t < NT) {
            float m_new = mj[t];
            #pragma unroll
            for (int i = 0; i < TI; ++i) m_new = fmaxf(m_new, pt[t][i]);
            aj[t] = __expf(mj[t] - m_new);   // 0 on first tile (underflow)
            mj[t] = m_new;
        }
        __syncthreads();

        // exponentiate in place
        #pragma unroll
        for (int q = 0; q < 2; ++q) {
            int idx = t + q * 256;
            int i = idx >> 4, jj = idx & (NT - 1);
            pt[jj][i] = __expf(pt[jj][i] - mj[jj]);
        }
        __syncthreads();

        // running denominator (t<16) + accumulate (all threads)
        if (t < NT) {
            float sum = 0.f;
            #pragma unroll
            for (int i = 0; i < TI; ++i) sum += pt[t][i];
            lj[t] = lj[t] * aj[t] + sum;
        }
        float alpha = aj[j];
        #pragma unroll
        for (int cc = 0; cc < 16; ++cc) acc[cc] *= alpha;
        #pragma unroll
        for (int i4 = 0; i4 < TI / 4; ++i4) {
            float4 p = *(const float4*)&pt[j][i4 * 4];
            #pragma unroll
            for (int cc = 0; cc < 16; ++cc) {
                float4 hv = *(const float4*)&hs[csub + 16 * cc][i4 * 4];
                acc[cc] += p.x * hv.x + p.y * hv.y + p.z * hv.z + p.w * hv.w;
            }
        }
        __syncthreads();
    }

    float scale = gamma[0] / lj[j];
    #pragma unroll
    for (int cc = 0; cc < 16; ++cc)
        out[((size_t)b * CC + (csub + 16 * cc)) * NN + j0 + j] = acc[cc] * scale;
}

extern "C" void kernel_launch(void* const* d_in, const int* in_sizes, int n_in,
                              void* d_out, int out_size, void* d_ws, size_t ws_size,
                              hipStream_t stream) {
    const float* x     = (const float*)d_in[0];
    const float* Wq    = (const float*)d_in[1];
    const float* bq    = (const float*)d_in[2];
    const float* Wk    = (const float*)d_in[3];
    const float* bk    = (const float*)d_in[4];
    const float* Wv    = (const float*)d_in[5];
    const float* bv    = (const float*)d_in[6];
    const float* gamma = (const float*)d_in[7];
    float* out = (float*)d_out;

    float* f = (float*)d_ws;                       // [B][CK][N]  2 MB
    float* g = f + (size_t)BB * CKK * NN;          // [B][CK][N]  2 MB
    float* h = g + (size_t)BB * CKK * NN;          // [B][C][N]  16 MB

    proj_kernel<<<BB * (NN / NT), 256, 0, stream>>>(x, Wq, bq, Wk, bk, Wv, bv, f, g, h);
    attn_kernel<<<BB * (NN / NT), 256, 0, stream>>>(f, g, h, gamma, out);
}

// Round 2
// 408.462 us; speedup vs baseline: 3.8721x; 3.8721x over previous
//
#include <hip/hip_runtime.h>
#include <math.h>

#define BB 4
#define CC 256
#define CKK 32
#define NN 4096
#define NT 16   // output columns (j) per block
#define TI 32   // key (i) tile

typedef __attribute__((ext_vector_type(8))) short short8v;   // bf16 x8 frag (4 VGPR)
typedef __attribute__((ext_vector_type(4))) short short4v;   // 8B
typedef __attribute__((ext_vector_type(4))) float f32x4;     // C/D frag
typedef __attribute__((ext_vector_type(4))) unsigned int uint4v; // 16B

static __device__ inline unsigned short f2bf(float x) {
    union { float f; unsigned u; } v; v.f = x;
    unsigned r = v.u + 0x7fffu + ((v.u >> 16) & 1u);   // RNE
    return (unsigned short)(r >> 16);
}

// ---------------- projection: fT/gT = (Wq/Wk x + b)^T as bf16 [b][n][32]; h bf16 [b][c][n]
__global__ __launch_bounds__(256) void proj_kernel(
    const float* __restrict__ x,
    const float* __restrict__ Wq, const float* __restrict__ bq,
    const float* __restrict__ Wk, const float* __restrict__ bk,
    const float* __restrict__ Wv, const float* __restrict__ bv,
    unsigned short* __restrict__ fT, unsigned short* __restrict__ gT,
    unsigned short* __restrict__ hB)
{
    __shared__ float xs[CC][17];
    const int t = threadIdx.x;
    const int b = blockIdx.x / (NN / NT);
    const int n0 = (blockIdx.x % (NN / NT)) * NT;

    {
        const float4* xp = (const float4*)(x + ((size_t)b * CC + t) * NN + n0);
        #pragma unroll
        for (int q = 0; q < NT / 4; ++q) {
            float4 v = xp[q];
            xs[t][q * 4 + 0] = v.x; xs[t][q * 4 + 1] = v.y;
            xs[t][q * 4 + 2] = v.z; xs[t][q * 4 + 3] = v.w;
        }
    }
    __syncthreads();

    const int n = t & (NT - 1);
    const int rsub = t >> 4;   // 0..15
    for (int riter = 0; riter < 20; ++riter) {
        int row = riter * 16 + rsub;           // 0..319
        const float* Wrow; float bias;
        if (row < 32)      { Wrow = Wq + (size_t)row * CC;        bias = bq[row]; }
        else if (row < 64) { Wrow = Wk + (size_t)(row - 32) * CC; bias = bk[row - 32]; }
        else               { Wrow = Wv + (size_t)(row - 64) * CC; bias = bv[row - 64]; }
        float acc = bias;
        #pragma unroll 8
        for (int c = 0; c < CC; c += 4) {
            float4 w = *(const float4*)(Wrow + c);
            acc += w.x * xs[c][n] + w.y * xs[c + 1][n]
                 + w.z * xs[c + 2][n] + w.w * xs[c + 3][n];
        }
        unsigned short bfv = f2bf(acc);
        if (row < 32)      fT[((size_t)b * NN + n0 + n) * CKK + row] = bfv;
        else if (row < 64) gT[((size_t)b * NN + n0 + n) * CKK + (row - 32)] = bfv;
        else               hB[((size_t)b * CC + (row - 64)) * NN + n0 + n] = bfv;
    }
}

// ---------------- fused attention with bf16 MFMA --------------------------------
// Per block: batch b, 16 output columns j. S[i][j] = sum_k f[k][i] g[k][j],
// softmax over i (online), O[c][j] = sum_i h[c][i] p[i][j].
__global__ __launch_bounds__(256) void attn_kernel(
    const unsigned short* __restrict__ fT,  // [B][N][CK] bf16
    const unsigned short* __restrict__ gT,  // [B][N][CK] bf16
    const unsigned short* __restrict__ hB,  // [B][C][N]  bf16
    const float* __restrict__ gamma,
    float* __restrict__ out)
{
    __shared__ unsigned short ft[32 * 40];    // [i_local][k], row stride 40 (80B)
    __shared__ unsigned short ht[CC * 40];    // [c][i_local], row stride 40
    __shared__ unsigned short pa[64 * 8];     // B-fragment-linear p: [lane][jj]
    __shared__ float ajs[NT];
    __shared__ float ljs[NT];

    const int t    = threadIdx.x;
    const int lane = t & 63;
    const int wave = t >> 6;
    const int g    = blockIdx.x;
    const int b    = g & 3;                   // XCD-affine: one batch per XCD
    const int j0   = (g >> 2) * NT;
    const int jl   = lane & 15;
    const int quad = lane >> 4;

    const unsigned short* fTb = fT + (size_t)b * NN * CKK;
    const unsigned short* hb  = hB + (size_t)b * CC * NN;

    // wave0 holds the g B-fragment in registers for the whole loop
    short8v bg;
    if (wave == 0)
        bg = *(const short8v*)(gT + ((size_t)b * NN + j0 + jl) * CKK + quad * 8);

    f32x4 acc[4];
    #pragma unroll
    for (int cb = 0; cb < 4; ++cb) acc[cb] = (f32x4){0.f, 0.f, 0.f, 0.f};
    float m_run = -1e30f, l_run = 0.f;

    for (int i0 = 0; i0 < NN; i0 += TI) {
        // stage f tile: [32 i][32 k], 8B per thread
        {
            int i = t >> 3, k0 = (t & 7) * 4;
            *(short4v*)&ft[i * 40 + k0] =
                *(const short4v*)(fTb + (size_t)(i0 + i) * CKK + k0);
        }
        // stage h tile: [256 c][32 i], 4 x 16B per thread
        #pragma unroll
        for (int q = 0; q < 4; ++q) {
            int chunk = q * 256 + t;
            int c = chunk >> 2, off = (chunk & 3) * 8;
            *(uint4v*)&ht[c * 40 + off] =
                *(const uint4v*)(hb + (size_t)c * NN + i0 + off);
        }
        __syncthreads();

        if (wave == 0) {
            short8v a0 = *(const short8v*)&ft[jl * 40 + quad * 8];
            short8v a1 = *(const short8v*)&ft[(16 + jl) * 40 + quad * 8];
            f32x4 z = (f32x4){0.f, 0.f, 0.f, 0.f};
            f32x4 s0 = __builtin_amdgcn_mfma_f32_16x16x32_bf16(a0, bg, z, 0, 0, 0);
            f32x4 s1 = __builtin_amdgcn_mfma_f32_16x16x32_bf16(a1, bg, z, 0, 0, 0);

            float mx = s0[0];
            #pragma unroll
            for (int r = 1; r < 4; ++r) mx = fmaxf(mx, s0[r]);
            #pragma unroll
            for (int r = 0; r < 4; ++r) mx = fmaxf(mx, s1[r]);
            mx = fmaxf(mx, __shfl_xor(mx, 16, 64));
            mx = fmaxf(mx, __shfl_xor(mx, 32, 64));

            float m_new = fmaxf(m_run, mx);
            float alpha = __expf(m_run - m_new);
            m_run = m_new;

            float p0[4], p1[4], ls = 0.f;
            #pragma unroll
            for (int r = 0; r < 4; ++r) { p0[r] = __expf(s0[r] - m_new); ls += p0[r]; }
            #pragma unroll
            for (int r = 0; r < 4; ++r) { p1[r] = __expf(s1[r] - m_new); ls += p1[r]; }
            ls += __shfl_xor(ls, 16, 64);
            ls += __shfl_xor(ls, 32, 64);
            l_run = l_run * alpha + ls;

            if (lane < NT) ajs[lane] = alpha;

            // p -> B-fragment-linear LDS (pa[L][jj] = p[i = (L>>4)*8 + jj][j = L&15])
            short4v v0, v1;
            #pragma unroll
            for (int r = 0; r < 4; ++r) { v0[r] = (short)f2bf(p0[r]); v1[r] = (short)f2bf(p1[r]); }
            int ib0 = quad * 4;
            int ib1 = 16 + quad * 4;
            *(short4v*)&pa[(jl + 16 * (ib0 >> 3)) * 8 + (ib0 & 7)] = v0;
            *(short4v*)&pa[(jl + 16 * (ib1 >> 3)) * 8 + (ib1 & 7)] = v1;
        }
        __syncthreads();

        float alpha = ajs[jl];
        #pragma unroll
        for (int cb = 0; cb < 4; ++cb) {
            #pragma unroll
            for (int r = 0; r < 4; ++r) acc[cb][r] *= alpha;
        }
        short8v bp = *(const short8v*)&pa[lane * 8];
        #pragma unroll
        for (int cb = 0; cb < 4; ++cb) {
            int c0 = (wave * 4 + cb) * 16 + jl;
            short8v a = *(const short8v*)&ht[c0 * 40 + quad * 8];
            acc[cb] = __builtin_amdgcn_mfma_f32_16x16x32_bf16(a, bp, acc[cb], 0, 0, 0);
        }
        __syncthreads();   // protect ft/ht/pa before next staging
    }

    if (wave == 0 && lane < NT) ljs[lane] = l_run;
    __syncthreads();

    float scale = gamma[0] / ljs[jl];
    #pragma unroll
    for (int cb = 0; cb < 4; ++cb) {
        int cbase = (wave * 4 + cb) * 16 + quad * 4;
        #pragma unroll
        for (int r = 0; r < 4; ++r)
            out[((size_t)b * CC + cbase + r) * NN + j0 + jl] = acc[cb][r] * scale;
    }
}

extern "C" void kernel_launch(void* const* d_in, const int* in_sizes, int n_in,
                              void* d_out, int out_size, void* d_ws, size_t ws_size,
                              hipStream_t stream) {
    const float* x     = (const float*)d_in[0];
    const float* Wq    = (const float*)d_in[1];
    const float* bq    = (const float*)d_in[2];
    const float* Wk    = (const float*)d_in[3];
    const float* bk    = (const float*)d_in[4];
    const float* Wv    = (const float*)d_in[5];
    const float* bv    = (const float*)d_in[6];
    const float* gamma = (const float*)d_in[7];
    float* out = (float*)d_out;

    unsigned short* fT = (unsigned short*)d_ws;                 // 1 MB
    unsigned short* gT = fT + (size_t)BB * NN * CKK;            // 1 MB
    unsigned short* hB = gT + (size_t)BB * NN * CKK;            // 8 MB

    proj_kernel<<<BB * (NN / NT), 256, 0, stream>>>(x, Wq, bq, Wk, bk, Wv, bv, fT, gT, hB);
    attn_kernel<<<BB * (NN / NT), 256, 0, stream>>>(fT, gT, hB, gamma, out);
}

// Round 3
// 234.496 us; speedup vs baseline: 6.7447x; 1.7419x over previous
//
#include <hip/hip_runtime.h>
#include <math.h>

#define BB 4
#define CC 256
#define CKK 32
#define NN 4096
#define JT 64      // j columns per attn block (16 per wave)
#define TI 32      // key (i) tile

typedef __attribute__((ext_vector_type(8))) short short8v;   // bf16 x8 (4 VGPR)
typedef __attribute__((ext_vector_type(4))) short short4v;   // 8B
typedef __attribute__((ext_vector_type(4))) float f32x4;     // MFMA C/D
typedef __attribute__((ext_vector_type(4))) unsigned int uint4v; // 16B

static __device__ inline unsigned short f2bf(float x) {
    union { float f; unsigned u; } v; v.f = x;
    unsigned r = v.u + 0x7fffu + ((v.u >> 16) & 1u);   // RNE
    return (unsigned short)(r >> 16);
}
static __device__ inline float bf2f(unsigned short h) {
    union { unsigned u; float f; } v; v.u = ((unsigned)h) << 16;
    return v.f;
}

// ---------------- prep: W (Wq|Wk|Wv) -> bf16 [320][256] -------------------------
__global__ __launch_bounds__(256) void prep_w(
    const float* __restrict__ Wq, const float* __restrict__ Wk,
    const float* __restrict__ Wv, unsigned short* __restrict__ Wbf)
{
    int e = blockIdx.x * 256 + threadIdx.x;   // 320*256
    int row = e >> 8, c = e & 255;
    float v;
    if (row < 32)      v = Wq[row * 256 + c];
    else if (row < 64) v = Wk[(row - 32) * 256 + c];
    else               v = Wv[(row - 64) * 256 + c];
    Wbf[e] = f2bf(v);
}

// ---------------- projection GEMM via MFMA (x split hi/lo for ~fp32 accuracy) ----
// Outputs: fT/gT bf16 [b][n][32] (transposed), hB bf16 [b][c][n]
__global__ __launch_bounds__(256) void proj_kernel(
    const float* __restrict__ x,
    const unsigned short* __restrict__ Wbf,
    const float* __restrict__ bq, const float* __restrict__ bk,
    const float* __restrict__ bv,
    unsigned short* __restrict__ fT, unsigned short* __restrict__ gT,
    unsigned short* __restrict__ hB)
{
    __shared__ float xs[CC][40];               // x tile [c][n], stride 40
    __shared__ unsigned short xh[32][264];     // x^T hi  [n][c], stride 264 (16B-aligned)
    __shared__ unsigned short xl[32][264];     // x^T lo

    const int t = threadIdx.x;
    const int b = blockIdx.x >> 7;             // 128 blocks per batch
    const int n_b = (blockIdx.x & 127) * 32;   // 32 columns per block
    const int lane = t & 63;
    const int wave = t >> 6;
    const int jl = lane & 15;
    const int quad = lane >> 4;

    // stage x tile [256 c][32 n] fp32, coalesced (8 lanes per row)
    {
        int q = t & 7, c0 = t >> 3;
        #pragma unroll
        for (int cc = 0; cc < 8; ++cc) {
            int c = c0 + cc * 32;
            *(float4*)&xs[c][q * 4] =
                *(const float4*)(x + ((size_t)b * CC + c) * NN + n_b + q * 4);
        }
    }
    __syncthreads();

    // transpose + split to bf16 hi/lo
    {
        int n = t & 31, cbase = (t >> 5) * 32;
        #pragma unroll
        for (int ci = 0; ci < 32; ci += 2) {
            float v0 = xs[cbase + ci][n], v1 = xs[cbase + ci + 1][n];
            unsigned short h0 = f2bf(v0), h1 = f2bf(v1);
            unsigned short l0 = f2bf(v0 - bf2f(h0)), l1 = f2bf(v1 - bf2f(h1));
            *(unsigned*)&xh[n][cbase + ci] = (unsigned)h0 | ((unsigned)h1 << 16);
            *(unsigned*)&xl[n][cbase + ci] = (unsigned)l0 | ((unsigned)l1 << 16);
        }
    }
    __syncthreads();

    const int rowbase_w = wave * 80;   // 4 waves x 80 rows = 320
    #pragma unroll 1
    for (int nt = 0; nt < 2; ++nt) {
        short8v bhi[8], blo[8];
        #pragma unroll
        for (int k = 0; k < 8; ++k) {
            bhi[k] = *(const short8v*)&xh[nt * 16 + jl][k * 32 + quad * 8];
            blo[k] = *(const short8v*)&xl[nt * 16 + jl][k * 32 + quad * 8];
        }
        const int ng = n_b + nt * 16 + jl;   // column within batch (per lane)
        #pragma unroll 1
        for (int mt = 0; mt < 5; ++mt) {
            int rowbase = rowbase_w + mt * 16;
            const unsigned short* wrow = Wbf + (size_t)(rowbase + jl) * CC;
            f32x4 acc = (f32x4){0.f, 0.f, 0.f, 0.f};
            #pragma unroll
            for (int k = 0; k < 8; ++k) {
                short8v a = *(const short8v*)(wrow + k * 32 + quad * 8);
                acc = __builtin_amdgcn_mfma_f32_16x16x32_bf16(a, bhi[k], acc, 0, 0, 0);
                acc = __builtin_amdgcn_mfma_f32_16x16x32_bf16(a, blo[k], acc, 0, 0, 0);
            }
            int rlo = rowbase + quad * 4;   // lane's first of 4 output rows
            if (rowbase < 32) {
                float4 bias = *(const float4*)(bq + rlo);
                short4v o;
                o[0] = (short)f2bf(acc[0] + bias.x); o[1] = (short)f2bf(acc[1] + bias.y);
                o[2] = (short)f2bf(acc[2] + bias.z); o[3] = (short)f2bf(acc[3] + bias.w);
                *(short4v*)(fT + ((size_t)b * NN + ng) * CKK + rlo) = o;
            } else if (rowbase < 64) {
                float4 bias = *(const float4*)(bk + rlo - 32);
                short4v o;
                o[0] = (short)f2bf(acc[0] + bias.x); o[1] = (short)f2bf(acc[1] + bias.y);
                o[2] = (short)f2bf(acc[2] + bias.z); o[3] = (short)f2bf(acc[3] + bias.w);
                *(short4v*)(gT + ((size_t)b * NN + ng) * CKK + (rlo - 32)) = o;
            } else {
                const float* bp = bv + rlo - 64;
                #pragma unroll
                for (int r = 0; r < 4; ++r)
                    hB[((size_t)b * CC + rlo - 64 + r) * NN + ng] = f2bf(acc[r] + bp[r]);
            }
        }
    }
}

// ---------------- fused attention: 64 j/block, 16 j/wave, double-buffered -------
__global__ __launch_bounds__(256) void attn_kernel(
    const unsigned short* __restrict__ fT,  // [B][N][CK] bf16
    const unsigned short* __restrict__ gT,  // [B][N][CK] bf16
    const unsigned short* __restrict__ hB,  // [B][C][N]  bf16
    const float* __restrict__ gamma,
    float* __restrict__ out)
{
    __shared__ unsigned short ft[2][32 * 40];    // [i][k], stride 40
    __shared__ unsigned short ht[2][CC * 40];    // [c][i], stride 40
    __shared__ unsigned short pa[4][64 * 8];     // per-wave P in B-frag layout

    const int t = threadIdx.x;
    const int lane = t & 63;
    const int wave = t >> 6;
    const int b  = blockIdx.x & 3;                 // XCD-affine batches
    const int j0 = (blockIdx.x >> 2) * JT;
    const int jl = lane & 15;
    const int quad = lane >> 4;
    const int jw = j0 + wave * 16;                 // this wave's 16 columns

    const unsigned short* fTb = fT + (size_t)b * NN * CKK;
    const unsigned short* hb  = hB + (size_t)b * CC * NN;

    short8v bg = *(const short8v*)(gT + ((size_t)b * NN + jw + jl) * CKK + quad * 8);

    f32x4 acc[16];
    #pragma unroll
    for (int cb = 0; cb < 16; ++cb) acc[cb] = (f32x4){0.f, 0.f, 0.f, 0.f};
    float m_run = -1e30f, l_run = 0.f;

    const int fi = t >> 3, fk = (t & 7) * 4;       // ft staging: 8B/thread
    const int hc = t >> 2, ho = (t & 3) * 8;       // ht staging: 4x16B/thread

    short4v rf = *(const short4v*)(fTb + (size_t)fi * CKK + fk);
    uint4v rh[4];
    #pragma unroll
    for (int q = 0; q < 4; ++q)
        rh[q] = *(const uint4v*)(hb + (size_t)(q * 64 + hc) * NN + ho);

    for (int it = 0; it < NN / TI; ++it) {
        const int buf = it & 1;
        *(short4v*)&ft[buf][fi * 40 + fk] = rf;
        #pragma unroll
        for (int q = 0; q < 4; ++q)
            *(uint4v*)&ht[buf][(q * 64 + hc) * 40 + ho] = rh[q];
        __syncthreads();

        if (it + 1 < NN / TI) {   // prefetch next tile into regs (overlaps compute)
            int i0 = (it + 1) * TI;
            rf = *(const short4v*)(fTb + (size_t)(i0 + fi) * CKK + fk);
            #pragma unroll
            for (int q = 0; q < 4; ++q)
                rh[q] = *(const uint4v*)(hb + (size_t)(q * 64 + hc) * NN + i0 + ho);
        }

        // ---- QK: S[i 0..32][j 0..16] for this wave's j-group
        short8v a0 = *(const short8v*)&ft[buf][jl * 40 + quad * 8];
        short8v a1 = *(const short8v*)&ft[buf][(16 + jl) * 40 + quad * 8];
        f32x4 z = (f32x4){0.f, 0.f, 0.f, 0.f};
        f32x4 s0 = __builtin_amdgcn_mfma_f32_16x16x32_bf16(a0, bg, z, 0, 0, 0);
        f32x4 s1 = __builtin_amdgcn_mfma_f32_16x16x32_bf16(a1, bg, z, 0, 0, 0);

        // ---- online softmax over i (per-column j, reduce across quads)
        float mx = fmaxf(fmaxf(fmaxf(s0[0], s0[1]), fmaxf(s0[2], s0[3])),
                         fmaxf(fmaxf(s1[0], s1[1]), fmaxf(s1[2], s1[3])));
        mx = fmaxf(mx, __shfl_xor(mx, 16, 64));
        mx = fmaxf(mx, __shfl_xor(mx, 32, 64));
        float m_new = fmaxf(m_run, mx);
        float alpha = __expf(m_run - m_new);
        m_run = m_new;

        float p0[4], p1[4], ls = 0.f;
        #pragma unroll
        for (int r = 0; r < 4; ++r) { p0[r] = __expf(s0[r] - m_new); ls += p0[r]; }
        #pragma unroll
        for (int r = 0; r < 4; ++r) { p1[r] = __expf(s1[r] - m_new); ls += p1[r]; }
        ls += __shfl_xor(ls, 16, 64);
        ls += __shfl_xor(ls, 32, 64);
        l_run = l_run * alpha + ls;

        // ---- P -> B-fragment layout via wave-private LDS round-trip
        short4v v0, v1;
        #pragma unroll
        for (int r = 0; r < 4; ++r) { v0[r] = (short)f2bf(p0[r]); v1[r] = (short)f2bf(p1[r]); }
        {
            int ib0 = quad * 4, ib1 = 16 + quad * 4;
            *(short4v*)&pa[wave][(jl + 16 * (ib0 >> 3)) * 8 + (ib0 & 7)] = v0;
            *(short4v*)&pa[wave][(jl + 16 * (ib1 >> 3)) * 8 + (ib1 & 7)] = v1;
        }
        short8v bp = *(const short8v*)&pa[wave][lane * 8];

        if (__any(alpha != 1.0f)) {
            #pragma unroll
            for (int cb = 0; cb < 16; ++cb) {
                acc[cb][0] *= alpha; acc[cb][1] *= alpha;
                acc[cb][2] *= alpha; acc[cb][3] *= alpha;
            }
        }
        // ---- PV: O[c 0..256][j-group] += h-tile * P
        #pragma unroll
        for (int cb = 0; cb < 16; ++cb) {
            short8v a = *(const short8v*)&ht[buf][(cb * 16 + jl) * 40 + quad * 8];
            acc[cb] = __builtin_amdgcn_mfma_f32_16x16x32_bf16(a, bp, acc[cb], 0, 0, 0);
        }
    }

    float scale = gamma[0] / l_run;
    #pragma unroll
    for (int cb = 0; cb < 16; ++cb) {
        int c0 = cb * 16 + quad * 4;
        #pragma unroll
        for (int r = 0; r < 4; ++r)
            out[((size_t)b * CC + c0 + r) * NN + jw + jl] = acc[cb][r] * scale;
    }
}

extern "C" void kernel_launch(void* const* d_in, const int* in_sizes, int n_in,
                              void* d_out, int out_size, void* d_ws, size_t ws_size,
                              hipStream_t stream) {
    const float* x     = (const float*)d_in[0];
    const float* Wq    = (const float*)d_in[1];
    const float* bq    = (const float*)d_in[2];
    const float* Wk    = (const float*)d_in[3];
    const float* bk    = (const float*)d_in[4];
    const float* Wv    = (const float*)d_in[5];
    const float* bv    = (const float*)d_in[6];
    const float* gamma = (const float*)d_in[7];
    float* out = (float*)d_out;

    unsigned short* Wbf = (unsigned short*)d_ws;            // 320*256
    unsigned short* fT  = Wbf + 320 * 256;                  // [B][N][32]
    unsigned short* gT  = fT + (size_t)BB * NN * CKK;
    unsigned short* hB  = gT + (size_t)BB * NN * CKK;       // [B][C][N]

    prep_w<<<320, 256, 0, stream>>>(Wq, Wk, Wv, Wbf);
    proj_kernel<<<BB * (NN / 32), 256, 0, stream>>>(x, Wbf, bq, bk, bv, fT, gT, hB);
    attn_kernel<<<BB * (NN / JT), 256, 0, stream>>>(fT, gT, hB, gamma, out);
}